// Round 5
// baseline (300.120 us; speedup 1.0000x reference)
//
#include <hip/hip_runtime.h>
#include <hip/hip_bf16.h>
#include <math.h>

#define B_ 4
#define N_ 2048
#define D_ 1024
#define H_ 16
#define HD_ 64
#define SCALE_ 0.015625f   // 1/HD
#define MD_ ((size_t)B_ * N_ * D_)   // 8388608
#define DD_ ((size_t)D_ * D_)        // 1048576
#define BHSZ_ ((size_t)N_ * HD_)     // 131072 elems per (b,h) frag slab
// folded into q at RoPE: SCALE * log2(e)
#define QSC_ 0.0225421143f

typedef __hip_bfloat16 bf16;
typedef __attribute__((ext_vector_type(8))) __bf16 bf16x8;
typedef __attribute__((ext_vector_type(4))) float f32x4;
typedef __attribute__((ext_vector_type(16))) float f32x16;

__device__ __forceinline__ float b2f(bf16 x) { return __bfloat162float(x); }
__device__ __forceinline__ bf16 f2b(float x) { return __float2bfloat16(x); }

// exact (RNE) pack of two floats to bf16 pair (elem0 low)
__device__ __forceinline__ unsigned int pk2(float a, float b) {
  union { bf16 h[2]; unsigned int u; } t;
  t.h[0] = f2b(a); t.h[1] = f2b(b);
  return t.u;
}
// truncating pack (cheap; for P fragments only, e >= 0)
__device__ __forceinline__ unsigned int pk2t(float a, float b) {
  return (__float_as_uint(a) >> 16) | (__float_as_uint(b) & 0xffff0000u);
}

// async global->LDS, 16 bytes per lane
__device__ __forceinline__ void gl_lds16(const bf16* g, bf16* l) {
  __builtin_amdgcn_global_load_lds(
      (const __attribute__((address_space(1))) void*)g,
      (__attribute__((address_space(3))) void*)l, 16, 0, 0);
}

// raw barrier with compiler-level memory fences (no vmcnt drain)
__device__ __forceinline__ void fbar() {
  asm volatile("" ::: "memory");
  __builtin_amdgcn_s_barrier();
  asm volatile("" ::: "memory");
}

#define MFMA16(a, b, c) __builtin_amdgcn_mfma_f32_16x16x32_bf16((a), (b), (c), 0, 0, 0)

// ---------------------------------------------------------------------------
// Fused fp32 -> bf16 conversion of x, Wq, Wk, Wv, Wo, PLUS RoPE cos/sin
// table generation (blocks 6144..6207): rt[n*32 + i] = (cos, sin) of
// n * theta^(-i/32), 2048x32 float2 = 512 KB.
// ---------------------------------------------------------------------------
__global__ __launch_bounds__(256) void cvt_all(
    const float* __restrict__ x,  const float* __restrict__ wq,
    const float* __restrict__ wk, const float* __restrict__ wv,
    const float* __restrict__ wo, bf16* __restrict__ xb,
    bf16* __restrict__ wb, float2* __restrict__ rt)
{
  const int blk = blockIdx.x;
  if (blk >= 6144) {
    const float LN_THETA = 9.210340371976184f;
    int e = ((blk - 6144) * 256 + (int)threadIdx.x) * 4;
    float fn = (float)(e >> 5);
#pragma unroll
    for (int p = 0; p < 4; ++p) {
      int i = (e & 31) + p;
      float inv = __expf(-((float)(2 * i) / (float)HD_) * LN_THETA);
      float sv, cv;
      sincosf(fn * inv, &sv, &cv);
      rt[e + p] = make_float2(cv, sv);
    }
    return;
  }
  const float* s; bf16* d; int i;
  if (blk < 4096)      { s = x;  d = xb;           i = blk; }
  else if (blk < 4608) { s = wq; d = wb;           i = blk - 4096; }
  else if (blk < 5120) { s = wk; d = wb + DD_;     i = blk - 4608; }
  else if (blk < 5632) { s = wv; d = wb + 2 * DD_; i = blk - 5120; }
  else                 { s = wo; d = wb + 3 * DD_; i = blk - 5632; }
  int e = (i * 256 + threadIdx.x) * 8;
  float4 a = *reinterpret_cast<const float4*>(s + e);
  float4 b = *reinterpret_cast<const float4*>(s + e + 4);
  bf16 t[8] = {f2b(a.x), f2b(a.y), f2b(a.z), f2b(a.w),
               f2b(b.x), f2b(b.y), f2b(b.z), f2b(b.w)};
  *reinterpret_cast<int4*>(d + e) = *reinterpret_cast<const int4*>(t);
}

// ---------------------------------------------------------------------------
// QKV 8-phase GEMM at the m201 template geometry:
//   C[8192,3072] = xb @ [Wq;Wk;Wv]^T, frag-tiled + fused-RoPE epilogue.
//   BM=BN=256, BK=64, 8 waves (2M x 4N), per-wave output 128x64,
//   LDS 128 KiB = 2 dbuf x 2 k-half slabs x (A 256x32 + B 256x32).
// Phase = (k-half x C-half): 16 MFMA, 8 or 4 ds_read_b128, stage exactly one
// half-slab (2 x global_load_lds per wave -- SYMMETRIC across waves, so each
// wave's own vmcnt + barrier certifies collective staging).
// Counted vmcnt(4) only at phases 4 and 8 (once per K-tile); drain vmcnt(0)
// only in the tail iteration. 2 raw barriers/phase, setprio(1) around MFMA.
//
// Slot liveness (paper-verified): slab (buf,X,ks) is last read at the closing
// barrier of its second phase; its re-stage (tile t+2, same buf) issues >= 1
// phase later. Certification: vmcnt(4)+barrier at P4/P8 proves all waves'
// loads for the NEXT tile landed (last 2 half-slabs = 4 loads outstanding).
// LDS micro-layout: 16x32-col chunks with XOR slot swizzle (proven 0-conflict
// in rounds 0-4); readers use rsw = (quad ^ ((lm>>1)&3))*8.
// ---------------------------------------------------------------------------
__global__ __launch_bounds__(512, 2) void qkv8(
    const bf16* __restrict__ A, const bf16* __restrict__ W,
    bf16* __restrict__ Cv, const float2* __restrict__ rt)
{
  __shared__ bf16 As[2 * 2 * 16 * 512];   // [buf][ks][chunk16][512] = 64 KB
  __shared__ bf16 Bs[2 * 2 * 16 * 512];   // 64 KB

  const int tid  = threadIdx.x;
  const int w    = tid >> 6;          // 0..7
  const int lane = tid & 63;
  const int wm   = w >> 2;            // M half (128 rows)
  const int wn   = w & 3;             // N quarter (64 cols)
  const int lm   = lane & 15;
  const int quad = lane >> 4;

  // bijective XCD swizzle: 384 blocks = 48 per XCD
  const int wgid = (blockIdx.x & 7) * 48 + ((int)blockIdx.x >> 3);
  const int bn   = (wgid % 12) * 256;
  const int bm   = (wgid / 12) * 256;

  const int srow = lane >> 2;                        // 0..15 within chunk
  const int scol = ((lane & 3) ^ ((lane >> 3) & 3)) * 8;
  const int rsw  = (quad ^ ((lm >> 1) & 3)) * 8;

  const int K = 1024;

  f32x4 acc[8][4] = {};

  // stage half-slab (tile T, k-half ks): 16 chunks, wave stages 2w, 2w+1
  auto stA = [&](int T, int ks) {
    bf16* dst = &As[((T & 1) * 2 + ks) * 8192];
    size_t kc = (size_t)T * 64 + ks * 32 + scol;
#pragma unroll
    for (int j = 0; j < 2; ++j) {
      int c = 2 * w + j;
      gl_lds16(A + (size_t)(bm + c * 16 + srow) * K + kc, dst + c * 512);
    }
  };
  auto stB = [&](int T, int ks) {
    bf16* dst = &Bs[((T & 1) * 2 + ks) * 8192];
    size_t kc = (size_t)T * 64 + ks * 32 + scol;
#pragma unroll
    for (int j = 0; j < 2; ++j) {
      int c = 2 * w + j;
      gl_lds16(W + (size_t)(bn + c * 16 + srow) * K + kc, dst + c * 512);
    }
  };

  auto rdA1 = [&](int T, int ks, int mi) -> bf16x8 {
    return *reinterpret_cast<const bf16x8*>(
        &As[(((T & 1) * 2 + ks) * 16 + wm * 8 + mi) * 512 + lm * 32 + rsw]);
  };
  auto rdB1 = [&](int T, int ks, int ni) -> bf16x8 {
    return *reinterpret_cast<const bf16x8*>(
        &Bs[(((T & 1) * 2 + ks) * 16 + wn * 4 + ni) * 512 + lm * 32 + rsw]);
  };

  bf16x8 bb[4];

  // PHASE(T, KS, MH, RB, STAGE_STMT, WN):
  //   reads A-frags (MH half) and (if RB) B-frags of (T,KS); issues stage;
  //   barrier; lgkmcnt(0); setprio; 16 MFMA; setprio; [vmcnt(WN)]; barrier.
#define PHASE(T, KS, MH, RB, STAGE_STMT, WN) do {                             \
    bf16x8 af_[4];                                                            \
    _Pragma("unroll") for (int i_ = 0; i_ < 4; ++i_)                          \
      af_[i_] = rdA1((T), (KS), (MH) * 4 + i_);                               \
    if (RB) { _Pragma("unroll") for (int i_ = 0; i_ < 4; ++i_)                \
      bb[i_] = rdB1((T), (KS), i_); }                                         \
    STAGE_STMT;                                                               \
    fbar();                                                                   \
    asm volatile("s_waitcnt lgkmcnt(0)" ::: "memory");                        \
    __builtin_amdgcn_s_setprio(1);                                            \
    _Pragma("unroll") for (int i_ = 0; i_ < 4; ++i_)                          \
      _Pragma("unroll") for (int n_ = 0; n_ < 4; ++n_)                        \
        acc[(MH) * 4 + i_][n_] = MFMA16(af_[i_], bb[n_], acc[(MH) * 4 + i_][n_]); \
    __builtin_amdgcn_s_setprio(0);                                            \
    if ((WN) == 4) asm volatile("s_waitcnt vmcnt(4)" ::: "memory");           \
    if ((WN) == 0) asm volatile("s_waitcnt vmcnt(0)" ::: "memory");           \
    fbar();                                                                   \
  } while (0)

  // prologue: tile0 full (4 half-slabs) + tile1 k0 (2 half-slabs) = 12 loads;
  // vmcnt(4) certifies tile0 landed (tile1-k0's 4 loads stay in flight).
  stA(0, 0); stB(0, 0); stA(0, 1); stB(0, 1);
  stA(1, 0); stB(1, 0);
  asm volatile("s_waitcnt vmcnt(4)" ::: "memory");
  fbar();

  // steady state: 7 full iterations (tiles 0..13), stages always valid
  for (int t = 0; t < 14; t += 2) {
    PHASE(t,     0, 0, 1, { stA(t + 1, 1); }, -1);   // P1
    PHASE(t,     0, 1, 0, { stB(t + 1, 1); }, -1);   // P2
    PHASE(t,     1, 0, 1, { stA(t + 2, 0); }, -1);   // P3
    PHASE(t,     1, 1, 0, { stB(t + 2, 0); },  4);   // P4  certify t+1
    PHASE(t + 1, 0, 0, 1, { stA(t + 2, 1); }, -1);   // P5
    PHASE(t + 1, 0, 1, 0, { stB(t + 2, 1); }, -1);   // P6
    PHASE(t + 1, 1, 0, 1, { stA(t + 3, 0); }, -1);   // P7
    PHASE(t + 1, 1, 1, 0, { stB(t + 3, 0); },  4);   // P8  certify t+2
  }
  // tail iteration: tiles 14,15 — stage only (15,k1); drain once at P4.
  {
    const int t = 14;
    PHASE(t,     0, 0, 1, { stA(t + 1, 1); }, -1);
    PHASE(t,     0, 1, 0, { stB(t + 1, 1); }, -1);
    PHASE(t,     1, 0, 1, { ; },              -1);
    PHASE(t,     1, 1, 0, { ; },               0);   // certify tile 15 fully
    PHASE(t + 1, 0, 0, 1, { ; },              -1);
    PHASE(t + 1, 0, 1, 0, { ; },              -1);
    PHASE(t + 1, 1, 0, 1, { ; },              -1);
    PHASE(t + 1, 1, 1, 0, { ; },              -1);
  }
#undef PHASE

  // frag-tiled scatter epilogue with fused RoPE (verified round 4)
#pragma unroll
  for (int mi = 0; mi < 8; ++mi) {
#pragma unroll
    for (int r = 0; r < 4; ++r) {
      int row = bm + wm * 128 + mi * 16 + quad * 4 + r;
#pragma unroll
      for (int ni = 0; ni < 4; ++ni) {
        int col = bn + wn * 64 + ni * 16 + lm;
        float v = acc[mi][ni][r];
        int reg = col >> 10;            // 0=q, 1=k, 2=v
        int cc  = col & 1023;
        int bb2 = row >> 11;            // N_ == 2048
        int n   = row & (N_ - 1);
        int hh  = cc >> 6;
        int dd  = cc & 63;
        // RoPE partner: col^1 lives in lane^1, same acc slot
        float po = __shfl_xor(v, 1);
        if (reg < 2) {
          float2 cs = rt[(n << 5) + (dd >> 1)];
          v = (dd & 1) ? (v * cs.x + po * cs.y)
                       : (v * cs.x - po * cs.y);
          if (reg == 0) v *= QSC_;
          // F[bh][t32][s][hi][m][8]: d = 16s+8hi+j, m = n&31
          int t32 = n >> 5, m = n & 31;
          int s = dd >> 4, hb = (dd >> 3) & 1, j = dd & 7;
          Cv[(size_t)reg * MD_ +
             (size_t)(bb2 * H_ + hh) * BHSZ_ +
             (size_t)t32 * 2048 + s * 512 + hb * 256 + m * 8 + j] = f2b(v);
        } else {
          // Vf[bh][t32][hf][hi][hd][8]; key = 32*t32 + 16*hf + 8*hi + j
          int t32 = n >> 5, kk = n & 31;
          int hf = kk >> 4, hb = (kk >> 3) & 1, j = kk & 7;
          Cv[2 * MD_ +
             (size_t)(bb2 * H_ + hh) * BHSZ_ +
             (size_t)t32 * 2048 + hf * 1024 + hb * 512 + dd * 8 + j] = f2b(v);
        }
      }
    }
  }
}

// ---------------------------------------------------------------------------
// Output-projection GEMM (round-0 VERIFIED structure): C = A @ W^T + bias,
// fp32 out. 128x128 tile, BK=32, 4 waves.
// ---------------------------------------------------------------------------
__global__ __launch_bounds__(256) void pgemm(
    const bf16* __restrict__ A, const bf16* __restrict__ W,
    const float* __restrict__ bias, float* __restrict__ C,
    int M, int N, int K)
{
  __shared__ bf16 As[128 * 32];
  __shared__ bf16 Ws[128 * 32];

  const int tid  = threadIdx.x;
  const int w    = tid >> 6;
  const int lane = tid & 63;
  const int bm   = blockIdx.y * 128;
  const int bn   = blockIdx.x * 128;

  const int wr = (w >> 1) * 64;
  const int wc = (w & 1) * 64;
  const int lm   = lane & 15;
  const int quad = lane >> 4;

  const int srow = lane >> 2;
  const int sslot = (lane & 3) ^ ((lane >> 3) & 3);
  const int scol = sslot * 8;
  const int rsw  = (quad ^ ((lm >> 1) & 3)) * 8;

  f32x4 acc[4][4] = {};

  for (int k0 = 0; k0 < K; k0 += 32) {
#pragma unroll
    for (int cc = 0; cc < 2; ++cc) {
      int c = w * 2 + cc;
      int r = c * 16 + srow;
      gl_lds16(A + (size_t)(bm + r) * K + k0 + scol, &As[c * 512]);
      gl_lds16(W + (size_t)(bn + r) * K + k0 + scol, &Ws[c * 512]);
    }
    __syncthreads();

    bf16x8 af[4], bf_[4];
#pragma unroll
    for (int mi = 0; mi < 4; ++mi)
      af[mi] = *reinterpret_cast<const bf16x8*>(&As[(wr + mi * 16 + lm) * 32 + rsw]);
#pragma unroll
    for (int ni = 0; ni < 4; ++ni)
      bf_[ni] = *reinterpret_cast<const bf16x8*>(&Ws[(wc + ni * 16 + lm) * 32 + rsw]);

#pragma unroll
    for (int mi = 0; mi < 4; ++mi)
#pragma unroll
      for (int ni = 0; ni < 4; ++ni)
        acc[mi][ni] = __builtin_amdgcn_mfma_f32_16x16x32_bf16(
            af[mi], bf_[ni], acc[mi][ni], 0, 0, 0);
    __syncthreads();
  }

#pragma unroll
  for (int mi = 0; mi < 4; ++mi) {
#pragma unroll
    for (int r = 0; r < 4; ++r) {
      int row = bm + wr + mi * 16 + quad * 4 + r;
#pragma unroll
      for (int ni = 0; ni < 4; ++ni) {
        int col = bn + wc + ni * 16 + lm;
        C[(size_t)row * N + col] = acc[mi][ni][r] + bias[col];
      }
    }
  }
}

// ---------------------------------------------------------------------------
// Flash attention v4 (unchanged — verified).
// ---------------------------------------------------------------------------
__global__ __launch_bounds__(128) void fattn4_kernel(
    const bf16* __restrict__ Qf, const bf16* __restrict__ Kf,
    const bf16* __restrict__ Vf, bf16* __restrict__ O)
{
  __shared__ float Ls[32 * 64];
  __shared__ float Ll[64];

  const int wv   = threadIdx.x >> 6;       // key-split half 0/1
  const int lane = threadIdx.x & 63;
  const int blk  = blockIdx.x;             // 0..4095
  const int xcd  = blk & 7;
  const int j    = blk >> 3;               // 0..511
  const int qt   = 63 - (j >> 3);          // big q-tiles dispatched first
  const int bh   = xcd * 8 + (j & 7);      // 8 bh per XCD group
  const int b    = bh >> 4;
  const int h    = bh & 15;
  const int col  = lane & 31;              // q-row / hd-row within frag
  const int hi   = lane >> 5;              // lane half

  const bf16* Qb = Qf + (size_t)bh * BHSZ_ + (size_t)qt * 2048 + hi * 256 + col * 8;
  const bf16* Kb = Kf + (size_t)bh * BHSZ_ + hi * 256 + col * 8;
  const bf16* Vb = Vf + (size_t)bh * BHSZ_ + hi * 512 + col * 8;

  bf16x8 qb[4];
#pragma unroll
  for (int s = 0; s < 4; ++s)
    qb[s] = *reinterpret_cast<const bf16x8*>(Qb + s * 512);

  f32x16 o0 = {}, o1 = {};
  float lsum = 0.f;

  for (int kst = wv; kst <= qt; kst += 2) {
    const bf16* kp = Kb + (size_t)kst * 2048;
    f32x16 st = {};
#pragma unroll
    for (int s = 0; s < 4; ++s) {
      bf16x8 ka = *reinterpret_cast<const bf16x8*>(kp + s * 512);
      st = __builtin_amdgcn_mfma_f32_32x32x16_bf16(ka, qb[s], st, 0, 0, 0);
    }

    float pe[16];
    if (kst == qt) {
#pragma unroll
      for (int r = 0; r < 16; ++r) {
        int koff = (r & 3) + 8 * (r >> 2) + 4 * hi;
        float e = (koff <= col) ? exp2f(st[r]) : 0.f;
        pe[r] = e; lsum += e;
      }
    } else {
#pragma unroll
      for (int r = 0; r < 16; ++r) {
        float e = exp2f(st[r]);
        pe[r] = e; lsum += e;
      }
    }

    const bf16* vp = Vb + (size_t)kst * 2048;
#pragma unroll
    for (int hf = 0; hf < 2; ++hf) {
      unsigned int a0 = pk2t(pe[8 * hf + 0], pe[8 * hf + 1]);
      unsigned int a1 = pk2t(pe[8 * hf + 2], pe[8 * hf + 3]);
      unsigned int b0 = pk2t(pe[8 * hf + 4], pe[8 * hf + 5]);
      unsigned int b1 = pk2t(pe[8 * hf + 6], pe[8 * hf + 7]);
      unsigned int s0 = hi ? a0 : b0;
      unsigned int s1 = hi ? a1 : b1;
      unsigned int r0 = (unsigned int)__shfl_xor((int)s0, 32);
      unsigned int r1 = (unsigned int)__shfl_xor((int)s1, 32);
      union { uint4 u; bf16x8 v; } pb;
      pb.u.x = hi ? r0 : a0;
      pb.u.y = hi ? r1 : a1;
      pb.u.z = hi ? b0 : r0;
      pb.u.w = hi ? b1 : r1;

      bf16x8 v0 = *reinterpret_cast<const bf16x8*>(vp + hf * 1024);
      bf16x8 v1 = *reinterpret_cast<const bf16x8*>(vp + hf * 1024 + 256);
      o0 = __builtin_amdgcn_mfma_f32_32x32x16_bf16(v0, pb.v, o0, 0, 0, 0);
      o1 = __builtin_amdgcn_mfma_f32_32x32x16_bf16(v1, pb.v, o1, 0, 0, 0);
    }
  }

  if (wv == 1) {
#pragma unroll
    for (int r = 0; r < 16; ++r) {
      Ls[r * 64 + lane]        = o0[r];
      Ls[(16 + r) * 64 + lane] = o1[r];
    }
    Ll[lane] = lsum;
  }
  __syncthreads();
  if (wv == 0) {
    float lt = lsum + Ll[lane];
    lt += __shfl_xor(lt, 32);
    float inv = 1.f / lt;
#pragma unroll
    for (int r = 0; r < 16; ++r) {
      o0[r] = (o0[r] + Ls[r * 64 + lane]) * inv;
      o1[r] = (o1[r] + Ls[(16 + r) * 64 + lane]) * inv;
    }
    bf16* Op = O + ((size_t)(b * N_ + 32 * qt + col)) * D_ + h * HD_;
#pragma unroll
    for (int g = 0; g < 4; ++g) {
      uint2 u;
      u.x = pk2(o0[4 * g + 0], o0[4 * g + 1]);
      u.y = pk2(o0[4 * g + 2], o0[4 * g + 3]);
      *reinterpret_cast<uint2*>(Op + 8 * g + 4 * hi) = u;
      u.x = pk2(o1[4 * g + 0], o1[4 * g + 1]);
      u.y = pk2(o1[4 * g + 2], o1[4 * g + 3]);
      *reinterpret_cast<uint2*>(Op + 32 + 8 * g + 4 * hi) = u;
    }
  }
}

// ---------------------------------------------------------------------------
extern "C" void kernel_launch(void* const* d_in, const int* in_sizes, int n_in,
                              void* d_out, int out_size, void* d_ws, size_t ws_size,
                              hipStream_t stream)
{
  const float* x  = (const float*)d_in[0];
  const float* Wq = (const float*)d_in[1];
  const float* Wk = (const float*)d_in[2];
  const float* Wv = (const float*)d_in[3];
  const float* Wo = (const float*)d_in[4];
  const float* bo = (const float*)d_in[5];
  float* out = (float*)d_out;

  const int M = B_ * N_;                    // 8192

  bf16* xb  = (bf16*)d_ws;                  // x bf16; dead after QKV -> ao
  bf16* qf  = xb + MD_;                     // Qf | Kf | Vf contiguous slabs
  bf16* kf  = qf + MD_;
  bf16* vf  = kf + MD_;
  bf16* Wqb = vf + MD_;                     // Wq|Wk|Wv|Wo bf16
  bf16* Wob = Wqb + 3 * DD_;
  float2* rt = (float2*)(Wqb + 4 * DD_);    // RoPE table: 2048x32 float2
  bf16* ao  = xb;

  // conversions + RoPE table
  cvt_all<<<6208, 256, 0, stream>>>(x, Wq, Wk, Wv, Wo, xb, Wqb, rt);

  // fused QKV + RoPE: 8-phase 256^2 template; 32 x 12 = 384 blocks
  qkv8<<<384, 512, 0, stream>>>(xb, Wqb, qf, rt);

  // one block (2 key-split waves) per (bh, 32-row q-tile): 4096 blocks
  fattn4_kernel<<<4096, 128, 0, stream>>>(qf, kf, vf, ao);

  // output proj (verified 128^2 structure)
  pgemm<<<dim3(8, 64), 256, 0, stream>>>(ao, Wob, bo, out, M, D_, D_);
}